// Round 12
// baseline (495.706 us; speedup 1.0000x reference)
//
#include <hip/hip_runtime.h>
#include <hip/hip_bf16.h>
#include <cmath>

// ---------------- problem constants ----------------
constexpr int B_ = 16, N_ = 577, C_ = 768, H_ = 12, D_ = 64, HID_ = 3072;
constexpr int ROWS_ = B_ * N_;   // 9232
constexpr int BH_ = B_ * H_;     // 192
constexpr int KVT_ = 10;         // kv tiles of 64
constexpr int QBLK_ = 10;        // q blocks of 64 per bh
constexpr int PSTR_ = 648;       // Pbig row stride (elems); 648*2=1296B, 1296/4%32=4

typedef __attribute__((ext_vector_type(8))) __bf16 bf16x8;
typedef __attribute__((ext_vector_type(4))) float f32x4;

#define DEVI __device__ __forceinline__

DEVI unsigned short f2bf(float f) {
  unsigned u = __float_as_uint(f);
  return (unsigned short)((u + 0x7fffu + ((u >> 16) & 1u)) >> 16);
}
DEVI float bf2f(unsigned short u) { return __uint_as_float(((unsigned)u) << 16); }

DEVI void gload16(const void* src, void* dst) {
  __builtin_amdgcn_global_load_lds(
      (const __attribute__((address_space(1))) char*)src,
      (__attribute__((address_space(3))) char*)dst, 16, 0, 0);
}
#define VMCNT0 asm volatile("s_waitcnt vmcnt(0)" ::: "memory")
#define VMW(n) asm volatile("s_waitcnt vmcnt(" #n ")" ::: "memory")
#define FENCE asm volatile("" ::: "memory")
#define RAWBAR do { FENCE; __builtin_amdgcn_s_barrier(); FENCE; } while (0)

// ---------------- merged transpose+cvt for all 4 weights ----------------
__global__ __launch_bounds__(256) void cvtAll_kernel(
    const float* __restrict__ a0, unsigned short* __restrict__ o0,
    const float* __restrict__ a1, unsigned short* __restrict__ o1,
    const float* __restrict__ a2, unsigned short* __restrict__ o2,
    const float* __restrict__ a3, unsigned short* __restrict__ o3) {
  __shared__ float t[64][65];
  int bid = blockIdx.x;
  const float* in; unsigned short* out; int K, N, nx;
  if (bid < 432) { in = a0; out = o0; K = 768; N = 2304; nx = 36; }
  else if (bid < 576) { bid -= 432; in = a1; out = o1; K = 768; N = 768; nx = 12; }
  else if (bid < 1152) { bid -= 576; in = a2; out = o2; K = 768; N = 3072; nx = 48; }
  else { bid -= 1152; in = a3; out = o3; K = 3072; N = 768; nx = 12; }
  int n0 = (bid % nx) * 64, k0 = (bid / nx) * 64;
  int tx = threadIdx.x & 63, ty = threadIdx.x >> 6;
#pragma unroll
  for (int r = 0; r < 16; r++) {
    int kr = ty * 16 + r;
    t[kr][tx] = in[(long)(k0 + kr) * N + n0 + tx];
  }
  __syncthreads();
#pragma unroll
  for (int r = 0; r < 16; r++) {
    int nr = ty * 16 + r;
    out[(long)(n0 + nr) * K + k0 + tx] = f2bf(t[tx][nr]);
  }
}

// ---------------- layernorm (768 = 3*256) ----------------
__global__ __launch_bounds__(256) void ln_kernel(const float* __restrict__ x,
                                                 const float* __restrict__ g,
                                                 const float* __restrict__ be,
                                                 unsigned short* __restrict__ out) {
  int row = blockIdx.x;
  const float* xr = x + (long)row * C_;
  float v[3];
  float s = 0.f, s2 = 0.f;
#pragma unroll
  for (int j = 0; j < 3; j++) {
    int i = threadIdx.x + j * 256;
    v[j] = xr[i];
    s += v[j];
    s2 += v[j] * v[j];
  }
#pragma unroll
  for (int o = 32; o > 0; o >>= 1) {
    s += __shfl_down(s, o);
    s2 += __shfl_down(s2, o);
  }
  __shared__ float sh[8];
  int w = threadIdx.x >> 6;
  if ((threadIdx.x & 63) == 0) { sh[w] = s; sh[4 + w] = s2; }
  __syncthreads();
  s = sh[0] + sh[1] + sh[2] + sh[3];
  s2 = sh[4] + sh[5] + sh[6] + sh[7];
  float mu = s * (1.f / C_);
  float var = s2 * (1.f / C_) - mu * mu;
  float rs = rsqrtf(var + 1e-5f);
#pragma unroll
  for (int j = 0; j < 3; j++) {
    int i = threadIdx.x + j * 256;
    out[(long)row * C_ + i] = f2bf((v[j] - mu) * rs * g[i] + be[i]);
  }
}

// ---------------- fused attention: swapped QK^T + LDS P panel + burst store --
// q,k: [BH][N][D] bf16 (q pre-scaled); vt: [BH][D][N] bf16
// attn out: [BH][N][N] fp32 written as one contiguous 148KB burst per block.
// No stores inside the vmcnt-gated loop -> gates are clean load-only counts.
__global__ __launch_bounds__(256) void attn_kernel(
    const unsigned short* __restrict__ qg,
    const unsigned short* __restrict__ kg,
    const unsigned short* __restrict__ vt,
    float* __restrict__ attn,
    unsigned short* __restrict__ ctx) {
  __shared__ unsigned short Ks[3][64][64];     // 24 KiB
  __shared__ unsigned short Vs[3][64][64];     // 24 KiB
  __shared__ unsigned short Pbig[64][PSTR_];   // 81 KiB, XOR-swizzled rows
  const int wgid = (blockIdx.x & 7) * (BH_ * QBLK_ / 8) + (blockIdx.x >> 3);
  const int bh = wgid / QBLK_, qb = wgid % QBLK_;
  const int b = bh / H_, h = bh % H_;
  const int tid = threadIdx.x, wave = tid >> 6, lane = tid & 63;
  const int l15 = lane & 15, l4 = lane >> 4;
  const int q0w = qb * 64 + wave * 16;

  const unsigned short* Qh = qg + (long)bh * N_ * D_;
  const char* Kb = (const char*)(kg + (long)bh * N_ * D_);
  const char* Vb = (const char*)(vt + (long)bh * D_ * N_);

  int qrc = q0w + l15; if (qrc >= N_) qrc = N_ - 1;
  bf16x8 qa0 = *(const bf16x8*)(Qh + (long)qrc * D_ + l4 * 8);
  bf16x8 qa1 = *(const bf16x8*)(Qh + (long)qrc * D_ + 32 + l4 * 8);

  auto srcAddr = [&](const char* g0, long rstride, int i) -> const char* {
    int off = i * 4096 + tid * 16;
    int row = off >> 7, colD = off & 127;
    return g0 + (long)row * rstride + (colD ^ ((row & 7) << 4));
  };
  auto stageK = [&](int bu, int kt) {
    const char* g0 = Kb + (long)kt * 8192;
#pragma unroll
    for (int i = 0; i < 2; i++)
      gload16(srcAddr(g0, 128, i), ((char*)Ks) + bu * 8192 + i * 4096 + wave * 1024);
  };
  auto stageV = [&](int bu, int kt) {
    const char* g0 = Vb + (long)kt * 128;
#pragma unroll
    for (int i = 0; i < 2; i++)
      gload16(srcAddr(g0, (long)N_ * 2, i), ((char*)Vs) + bu * 8192 + i * 4096 + wave * 1024);
  };
  auto rdK = [&](int bu, int row, int colb) -> bf16x8 {
    return *(const bf16x8*)(((const char*)Ks) + bu * 8192 + row * 128 +
                            (colb ^ ((row & 7) << 4)));
  };
  auto rdV = [&](int bu, int row, int colb) -> bf16x8 {
    return *(const bf16x8*)(((const char*)Vs) + bu * 8192 + row * 128 +
                            (colb ^ ((row & 7) << 4)));
  };
  // swapped: S^T = mfma(K, Q). Lane l15 owns q-row; kv = nf*16 + l4*4 + r.
  auto computeS = [&](int bu, f32x4 (&s)[4]) {
#pragma unroll
    for (int nf = 0; nf < 4; nf++) {
      int row = nf * 16 + l15;
      bf16x8 k0v = rdK(bu, row, l4 * 16);
      bf16x8 k1v = rdK(bu, row, 64 + l4 * 16);
      f32x4 z = {0.f, 0.f, 0.f, 0.f};
      z = __builtin_amdgcn_mfma_f32_16x16x32_bf16(k0v, qa0, z, 0, 0, 0);
      z = __builtin_amdgcn_mfma_f32_16x16x32_bf16(k1v, qa1, z, 0, 0, 0);
      s[nf] = z;
    }
  };
  auto maskLast = [&](f32x4 (&s)[4]) {  // kv tile 9: only kv=576 valid
#pragma unroll
    for (int nf = 0; nf < 4; nf++)
#pragma unroll
      for (int r = 0; r < 4; r++) {
        if (nf == 0 && r == 0)
          s[nf][r] = (l4 == 0) ? s[nf][r] : -1e30f;
        else
          s[nf][r] = -1e30f;
      }
  };

  // ---------- pass 1: K only, lane-local stats, 3-buffer depth-2 pipeline ----
  float m_ln = -1e30f, l_ln = 0.f;
  stageK(0, 0); stageK(1, 1);
#pragma unroll
  for (int kt = 0; kt < KVT_; kt++) {
    if (kt < KVT_ - 1) { VMW(2); } else { VMW(0); }
    RAWBAR;
    if (kt + 2 < KVT_) stageK((kt + 2) % 3, kt + 2);
    f32x4 s[4];
    computeS(kt % 3, s);
    if (kt == KVT_ - 1) maskLast(s);
    float mt = s[0][0];
#pragma unroll
    for (int nf = 0; nf < 4; nf++)
#pragma unroll
      for (int r = 0; r < 4; r++) mt = fmaxf(mt, s[nf][r]);
    float mn = fmaxf(m_ln, mt);
    float acc = 0.f;
#pragma unroll
    for (int nf = 0; nf < 4; nf++)
#pragma unroll
      for (int r = 0; r < 4; r++) acc += __expf(s[nf][r] - mn);
    l_ln = l_ln * __expf(m_ln - mn) + acc;
    m_ln = mn;
  }

  RAWBAR;  // all pass-1 LDS reads retired before restaging
  stageK(0, 0); stageV(0, 0); stageK(1, 1); stageV(1, 1);

  // cross-lane reduce over l4 group (overlaps prologue load latency)
  float m = fmaxf(m_ln, __shfl_xor(m_ln, 16));
  m = fmaxf(m, __shfl_xor(m, 32));
  float lr = l_ln * __expf(m_ln - m);
  lr += __shfl_xor(lr, 16);
  lr += __shfl_xor(lr, 32);
  float inv_l = 1.f / lr;

  // ---------- pass 2: P -> Pbig (LDS) + PV; loads-only vmcnt gates ----------
  f32x4 cacc[4];
#pragma unroll
  for (int nf = 0; nf < 4; nf++) cacc[nf] = f32x4{0.f, 0.f, 0.f, 0.f};

  const int prow_lds = wave * 16 + l15;         // this lane's q-row in Pbig
  char* pbase = ((char*)Pbig) + prow_lds * (PSTR_ * 2);
  const int pxor = (l15 & 7) << 4;              // row XOR key (wave*16 ≡ 0 mod 8)

#pragma unroll
  for (int kt = 0; kt < KVT_; kt++) {
    const int bu = kt % 3;
    if (kt < KVT_ - 1) { VMW(4); } else { VMW(0); }
    RAWBAR;
    if (kt + 2 < KVT_) { stageK((kt + 2) % 3, kt + 2); stageV((kt + 2) % 3, kt + 2); }
    f32x4 s[4];
    computeS(bu, s);
    if (kt == KVT_ - 1) maskLast(s);
    float p[4][4];
#pragma unroll
    for (int nf = 0; nf < 4; nf++)
#pragma unroll
      for (int r = 0; r < 4; r++) p[nf][r] = __expf(s[nf][r] - m) * inv_l;

    // pack bf16 (truncate) -> Pbig row (swizzled); kt=9 cols 576..639 hold 0s
#pragma unroll
    for (int nf = 0; nf < 4; nf++) {
      unsigned lo = (__float_as_uint(p[nf][1]) & 0xffff0000u) |
                    (__float_as_uint(p[nf][0]) >> 16);
      unsigned hi = (__float_as_uint(p[nf][3]) & 0xffff0000u) |
                    (__float_as_uint(p[nf][2]) >> 16);
      int colb = (kt * 64 + nf * 16 + l4 * 4) * 2;
      *(uint2*)(pbase + (colb ^ pxor)) = uint2{lo, hi};
    }
    // PV A-frag read back from Pbig (same-wave dep; compiler inserts lgkmcnt)
#pragma unroll
    for (int ks = 0; ks < 2; ks++) {
      int colb = (kt * 64 + ks * 32 + l4 * 8) * 2;
      bf16x8 pa = *(const bf16x8*)(pbase + (colb ^ pxor));
#pragma unroll
      for (int nf = 0; nf < 4; nf++) {
        bf16x8 vb = rdV(bu, nf * 16 + l15, ks * 64 + l4 * 16);
        cacc[nf] = __builtin_amdgcn_mfma_f32_16x16x32_bf16(pa, vb, cacc[nf], 0, 0, 0);
      }
    }
  }

  // ---------- ctx write (row = q = l4*4+r, col = d = nf*16+l15) ----------
#pragma unroll
  for (int nf = 0; nf < 4; nf++)
#pragma unroll
    for (int r = 0; r < 4; r++) {
      int qw = q0w + l4 * 4 + r;
      if (qw >= N_) continue;
      int d = nf * 16 + l15;
      ctx[((long)b * N_ + qw) * C_ + h * D_ + d] = f2bf(cacc[nf][r]);
    }

  // ---------- burst store: contiguous [vrows*577] region, sequential ----------
  __syncthreads();  // all waves' Pbig writes visible
  int vrows = N_ - qb * 64; if (vrows > 64) vrows = 64;
  float* base = attn + ((long)bh * N_ + (long)qb * 64) * N_;
  const long cnt = (long)vrows * N_;
  auto rdP = [&](unsigned f) -> float {
    unsigned row = f / 577u;
    unsigned col = f - row * 577u;
    const char* p = ((const char*)Pbig) + row * (PSTR_ * 2) +
                    ((col * 2) ^ ((row & 7) << 4));
    return bf2f(*(const unsigned short*)p);
  };
  int mis = (int)(((unsigned long)(uintptr_t)base >> 2) & 3);
  long head = (4 - mis) & 3; if (head > cnt) head = cnt;
  if (tid < head) __builtin_nontemporal_store(rdP(tid), base + tid);
  const long nb = (cnt - head) >> 2;
  for (long i = tid; i < nb; i += 256) {
    long f = head + i * 4;
    f32x4 v;
    v[0] = rdP((unsigned)f); v[1] = rdP((unsigned)f + 1);
    v[2] = rdP((unsigned)f + 2); v[3] = rdP((unsigned)f + 3);
    __builtin_nontemporal_store(v, (f32x4*)(base + f));
  }
  for (long f = head + nb * 4 + tid; f < cnt; f += 256)
    __builtin_nontemporal_store(rdP((unsigned)f), base + f);
}

// ---------------- 128x128 MFMA GEMM, counted-vmcnt 2-phase ----------------
template <int EPI>
__global__ __launch_bounds__(256) void gemm128(
    const unsigned short* __restrict__ A,
    const unsigned short* __restrict__ BT,
    int M, int K, int Nc,
    void* __restrict__ outp, const float* __restrict__ bias,
    const float* __restrict__ resid) {
  __shared__ unsigned short As[2][128][64];
  __shared__ unsigned short Bs[2][128][64];
  const int tid = threadIdx.x, wave = tid >> 6, lane = tid & 63;
  const int l15 = lane & 15, l4 = lane >> 4;
  const long m0 = (long)blockIdx.y * 128, n0 = (long)blockIdx.x * 128;
  const int wr = (wave >> 1) * 64, wc = (wave & 1) * 64;

  f32x4 acc[4][4];
#pragma unroll
  for (int i = 0; i < 4; i++)
#pragma unroll
    for (int j = 0; j < 4; j++) acc[i][j] = f32x4{0.f, 0.f, 0.f, 0.f};

  auto stageA = [&](int buf, int t) {
#pragma unroll
    for (int i = 0; i < 4; i++) {
      int off = i * 4096 + tid * 16;
      int row = off >> 7, colD = off & 127;
      long gr = m0 + row; if (gr >= M) gr = M - 1;
      const char* src = (const char*)A + (gr * (long)K + (long)t * 64) * 2 +
                        (colD ^ ((row & 7) << 4));
      char* dst = ((char*)As) + buf * 16384 + i * 4096 + wave * 1024;
      gload16(src, dst);
    }
  };
  auto stageB = [&](int buf, int t) {
#pragma unroll
    for (int i = 0; i < 4; i++) {
      int off = i * 4096 + tid * 16;
      int row = off >> 7, colD = off & 127;
      const char* src = (const char*)BT + ((n0 + row) * (long)K + (long)t * 64) * 2 +
                        (colD ^ ((row & 7) << 4));
      char* dst = ((char*)Bs) + buf * 16384 + i * 4096 + wave * 1024;
      gload16(src, dst);
    }
  };

  const int nt = K / 64;
  stageA(0, 0); stageB(0, 0);
  int buf = 0;
  for (int t = 0; t < nt; t++) {
    if (t + 1 < nt) {
      stageA(buf ^ 1, t + 1); stageB(buf ^ 1, t + 1);
      VMW(8);
    } else {
      VMCNT0;
    }
    RAWBAR;
    bf16x8 af[4][2], bfr[4][2];
#pragma unroll
    for (int mf = 0; mf < 4; mf++)
#pragma unroll
      for (int kk = 0; kk < 2; kk++) {
        int row = wr + mf * 16 + l15, colb = kk * 64 + l4 * 16;
        af[mf][kk] = *(const bf16x8*)(((const char*)As) + buf * 16384 + row * 128 +
                                      (colb ^ ((row & 7) << 4)));
      }
#pragma unroll
    for (int nf = 0; nf < 4; nf++)
#pragma unroll
      for (int kk = 0; kk < 2; kk++) {
        int row = wc + nf * 16 + l15, colb = kk * 64 + l4 * 16;
        bfr[nf][kk] = *(const bf16x8*)(((const char*)Bs) + buf * 16384 + row * 128 +
                                       (colb ^ ((row & 7) << 4)));
      }
#pragma unroll
    for (int kk = 0; kk < 2; kk++)
#pragma unroll
      for (int mf = 0; mf < 4; mf++)
#pragma unroll
        for (int nf = 0; nf < 4; nf++)
          acc[mf][nf] =
              __builtin_amdgcn_mfma_f32_16x16x32_bf16(af[mf][kk], bfr[nf][kk], acc[mf][nf], 0, 0, 0);
    RAWBAR;
    buf ^= 1;
  }

#pragma unroll
  for (int mf = 0; mf < 4; mf++)
#pragma unroll
    for (int nf = 0; nf < 4; nf++)
#pragma unroll
      for (int r = 0; r < 4; r++) {
        long row = m0 + wr + mf * 16 + l4 * 4 + r;
        long col = n0 + wc + nf * 16 + l15;
        if (row >= M) continue;
        float v = acc[mf][nf][r];
        if constexpr (EPI == 3 || EPI == 5) {
          float* o = (float*)outp;
          long idx = row * (long)Nc + col;
          o[idx] = v + bias[col] + resid[idx];
        } else if constexpr (EPI == 4) {
          v += bias[col];
          float ge = 0.5f * v * (1.f + erff(v * 0.70710678118654752f));
          ((unsigned short*)outp)[row * (long)Nc + col] = f2bf(ge);
        }
      }
}

// ---------------- 256x256 8-phase MFMA GEMM ----------------
template <int EPI>
__global__ __launch_bounds__(512, 2) void gemm256(
    const unsigned short* __restrict__ A,
    const unsigned short* __restrict__ BT,
    int M, int K, int Nc,
    void* __restrict__ outp, const float* __restrict__ bias,
    const float* __restrict__ resid) {
  __shared__ unsigned short smem[2][2][2][128][64];
  const int tid = threadIdx.x, wave = tid >> 6, lane = tid & 63;
  const int l15 = lane & 15, l4 = lane >> 4;
  const int wm = wave >> 2, wn = wave & 3;

  const int nbx = gridDim.x;
  const int nwg = nbx * gridDim.y;
  int orig = blockIdx.y * nbx + blockIdx.x;
  int qq = nwg >> 3, r8 = nwg & 7;
  int xcd = orig & 7, idx = orig >> 3;
  int wg = (xcd < r8 ? xcd * (qq + 1) : r8 * (qq + 1) + (xcd - r8) * qq) + idx;
  const long m0 = (long)(wg / nbx) * 256;
  const long n0 = (long)(wg % nbx) * 256;

  f32x4 acc[2][2][4][2];
#pragma unroll
  for (int a = 0; a < 2; a++)
#pragma unroll
    for (int b = 0; b < 2; b++)
#pragma unroll
      for (int m = 0; m < 4; m++)
#pragma unroll
        for (int n = 0; n < 2; n++) acc[a][b][m][n] = f32x4{0.f, 0.f, 0.f, 0.f};

  auto stage = [&](int d, int op, int half, int t) {
#pragma unroll
    for (int it = 0; it < 2; it++) {
      int off = it * 8192 + tid * 16;
      int lrow = off >> 7, colb = off & 127;
      long grow;
      if (op == 0) {
        grow = m0 + half * 128 + lrow;
        if (grow >= M) grow = M - 1;
      } else {
        grow = n0 + half * 128 + lrow;
      }
      const unsigned short* gp = (op == 0) ? A : BT;
      const char* src = (const char*)(gp + grow * (long)K + (long)t * 64) +
                        (colb ^ ((lrow & 7) << 4));
      char* dst = ((char*)smem) + (((d * 2 + op) * 2 + half) * 16384) + off;
      gload16(src, dst);
    }
  };
  auto rdfrag = [&](int d, int op, int half, int lr, int kk) -> bf16x8 {
    const char* p = ((const char*)smem) + (((d * 2 + op) * 2 + half) * 16384) + lr * 128 +
                    ((kk * 64 + l4 * 16) ^ ((lr & 7) << 4));
    return *(const bf16x8*)p;
  };

  bf16x8 av[4][2];

#define PHASE(d, qm, qn, STAGECODE, VMCODE)                                              \
  {                                                                                      \
    if constexpr (qn == 0) {                                                             \
      _Pragma("unroll") for (int m = 0; m < 4; m++)                                      \
          _Pragma("unroll") for (int kk = 0; kk < 2; kk++)                               \
              av[m][kk] = rdfrag(d, 0, qm, wm * 64 + m * 16 + l15, kk);                  \
    }                                                                                    \
    bf16x8 bv[2][2];                                                                     \
    _Pragma("unroll") for (int n = 0; n < 2; n++)                                        \
        _Pragma("unroll") for (int kk = 0; kk < 2; kk++)                                 \
            bv[n][kk] = rdfrag(d, 1, qn, wn * 32 + n * 16 + l15, kk);                    \
    STAGECODE;                                                                           \
    VMCODE;                                                                              \
    RAWBAR;                                                                              \
    __builtin_amdgcn_s_setprio(1);                                                       \
    _Pragma("unroll") for (int kk = 0; kk < 2; kk++)                                     \
        _Pragma("unroll") for (int m = 0; m < 4; m++)                                    \
            _Pragma("unroll") for (int n = 0; n < 2; n++)                                \
                acc[qm][qn][m][n] = __builtin_amdgcn_mfma_f32_16x16x32_bf16(             \
                    av[m][kk], bv[n][kk], acc[qm][qn][m][n], 0, 0, 0);                   \
    __builtin_amdgcn_s_setprio(0);                                                       \
    RAWBAR;                                                                              \
  }

  const int nt = K / 64, ni = nt / 2;
  stage(0, 0, 0, 0); stage(0, 0, 1, 0); stage(0, 1, 0, 0); stage(0, 1, 1, 0);
  stage(1, 0, 0, 1); stage(1, 0, 1, 1); stage(1, 1, 0, 1); stage(1, 1, 1, 1);
  asm volatile("s_waitcnt vmcnt(8)" ::: "memory");
  RAWBAR;

  for (int i = 0; i < ni; i++) {
    const int t1 = 2 * i + 1, t2 = 2 * i + 2, t3 = 2 * i + 3;
    PHASE(0, 0, 0, { if (i > 0) stage(1, 0, 1, t1); }, {});
    PHASE(0, 0, 1, { if (i > 0) stage(1, 1, 1, t1); }, {});
    PHASE(0, 1, 0, { if (t2 < nt) stage(0, 0, 0, t2); }, {});
    PHASE(0, 1, 1, { if (t2 < nt) stage(0, 1, 0, t2); },
          { if (t2 < nt) { asm volatile("s_waitcnt vmcnt(4)" ::: "memory"); }
            else { asm volatile("s_waitcnt vmcnt(0)" ::: "memory"); } });
    PHASE(1, 0, 0, { if (t2 < nt) stage(0, 0, 1, t2); }, {});
    PHASE(1, 0, 1, { if (t2 < nt) stage(0, 1, 1, t2); }, {});
    PHASE(1, 1, 0, { if (t3 < nt) stage(1, 0, 0, t3); }, {});
    PHASE(1, 1, 1, { if (t3 < nt) stage(1, 1, 0, t3); },
          { if (t3 < nt) { asm volatile("s_waitcnt vmcnt(4)" ::: "memory"); }
            else { asm volatile("s_waitcnt vmcnt(0)" ::: "memory"); } });
  }
#undef PHASE

#pragma unroll
  for (int qm = 0; qm < 2; qm++)
#pragma unroll
    for (int qn = 0; qn < 2; qn++)
#pragma unroll
      for (int m = 0; m < 4; m++)
#pragma unroll
        for (int n = 0; n < 2; n++)
#pragma unroll
          for (int r = 0; r < 4; r++) {
            long row = m0 + qm * 128 + wm * 64 + m * 16 + l4 * 4 + r;
            long col = n0 + qn * 128 + wn * 32 + n * 16 + l15;
            if (row >= M) continue;
            float v = acc[qm][qn][m][n][r];
            if constexpr (EPI == 0) {
              v += bias[col];
              int which = (int)col / C_;
              int rem = (int)col % C_;
              int hh = rem >> 6, d = rem & 63;
              int bb = (int)row / N_, nn = (int)row % N_;
              if (which == 0) v *= 0.125f;
              unsigned short* o = (unsigned short*)outp;
              long base = (long)which * ((long)BH_ * N_ * D_);
              long oidx;
              if (which < 2)
                oidx = base + (((long)(bb * H_ + hh)) * N_ + nn) * D_ + d;
              else
                oidx = base + (((long)(bb * H_ + hh)) * D_ + d) * N_ + nn;
              o[oidx] = f2bf(v);
            } else if constexpr (EPI == 4) {
              v += bias[col];
              float ge = 0.5f * v * (1.f + erff(v * 0.70710678118654752f));
              ((unsigned short*)outp)[row * (long)Nc + col] = f2bf(ge);
            } else {
              float* o = (float*)outp;
              long oidx = row * (long)Nc + col;
              o[oidx] = v + bias[col] + resid[oidx];
            }
          }
}

// ---------------- launch ----------------
extern "C" void kernel_launch(void* const* d_in, const int* in_sizes, int n_in,
                              void* d_out, int out_size, void* d_ws, size_t ws_size,
                              hipStream_t stream) {
  const float* x = (const float*)d_in[0];
  const float* w_qkv = (const float*)d_in[1];
  const float* b_qkv = (const float*)d_in[2];
  const float* w_proj = (const float*)d_in[3];
  const float* b_proj = (const float*)d_in[4];
  const float* g1 = (const float*)d_in[5];
  const float* be1 = (const float*)d_in[6];
  const float* g2 = (const float*)d_in[7];
  const float* be2 = (const float*)d_in[8];
  const float* w1 = (const float*)d_in[9];
  const float* b1 = (const float*)d_in[10];
  const float* w2 = (const float*)d_in[11];
  const float* b2 = (const float*)d_in[12];

  char* ws = (char*)d_ws;
  const size_t SZ_TOK_BF = (size_t)ROWS_ * C_ * 2;
  unsigned short* xn = (unsigned short*)(ws);
  unsigned short* q = (unsigned short*)(ws + SZ_TOK_BF);      // [BH][N][D]
  unsigned short* v = (unsigned short*)(ws + 3 * SZ_TOK_BF);  // [BH][D][N]
  unsigned short* ctx = (unsigned short*)(ws + 4 * SZ_TOK_BF);
  unsigned short* hbuf = q;  // reuse q/k/v/ctx area for MLP hidden
  float* x1 = (float*)(ws + 5 * SZ_TOK_BF);
  unsigned short* wqkvT = (unsigned short*)(ws + 5 * SZ_TOK_BF + (size_t)ROWS_ * C_ * 4);
  unsigned short* wprojT = wqkvT + (size_t)C_ * 3 * C_;
  unsigned short* w1T = wprojT + (size_t)C_ * C_;
  unsigned short* w2T = w1T + (size_t)C_ * HID_;

  float* out_x = (float*)d_out;
  float* attn = out_x + (size_t)ROWS_ * C_;

  cvtAll_kernel<<<1728, 256, 0, stream>>>(w_qkv, wqkvT, w_proj, wprojT, w1, w1T, w2, w2T);

  ln_kernel<<<ROWS_, 256, 0, stream>>>(x, g1, be1, xn);

  {  // QKV: 8-phase 256^2
    dim3 g(3 * C_ / 256, (ROWS_ + 255) / 256);
    gemm256<0><<<g, 512, 0, stream>>>(xn, wqkvT, ROWS_, C_, 3 * C_, q, b_qkv, nullptr);
  }
  attn_kernel<<<BH_ * QBLK_, 256, 0, stream>>>(q, q + (size_t)BH_ * N_ * D_, v, attn, ctx);
  {  // proj + residual
    dim3 g(C_ / 128, (ROWS_ + 127) / 128);
    gemm128<3><<<g, 256, 0, stream>>>(ctx, wprojT, ROWS_, C_, C_, x1, b_proj, x);
  }
  ln_kernel<<<ROWS_, 256, 0, stream>>>(x1, g2, be2, xn);
  {  // mlp1 + gelu: 8-phase 256^2
    dim3 g(HID_ / 256, (ROWS_ + 255) / 256);
    gemm256<4><<<g, 512, 0, stream>>>(xn, w1T, ROWS_, C_, HID_, hbuf, b1, nullptr);
  }
  {  // mlp2 + residual -> out_x
    dim3 g(C_ / 128, (ROWS_ + 127) / 128);
    gemm128<5><<<g, 256, 0, stream>>>(hbuf, w2T, ROWS_, HID_, C_, out_x, b2, x1);
  }
}

// Round 13
// 477.000 us; speedup vs baseline: 1.0392x; 1.0392x over previous
//
#include <hip/hip_runtime.h>
#include <hip/hip_bf16.h>
#include <cmath>

// ---------------- problem constants ----------------
constexpr int B_ = 16, N_ = 577, C_ = 768, H_ = 12, D_ = 64, HID_ = 3072;
constexpr int ROWS_ = B_ * N_;   // 9232
constexpr int BH_ = B_ * H_;     // 192
constexpr int KVT_ = 10;         // kv tiles of 64
constexpr int QBLK_ = 10;        // q blocks of 64 per bh

typedef __attribute__((ext_vector_type(8))) __bf16 bf16x8;
typedef __attribute__((ext_vector_type(4))) float f32x4;
typedef __attribute__((ext_vector_type(4), aligned(4))) float f32x4u;

#define DEVI __device__ __forceinline__

DEVI unsigned short f2bf(float f) {
  unsigned u = __float_as_uint(f);
  return (unsigned short)((u + 0x7fffu + ((u >> 16) & 1u)) >> 16);
}

DEVI void gload16(const void* src, void* dst) {
  __builtin_amdgcn_global_load_lds(
      (const __attribute__((address_space(1))) char*)src,
      (__attribute__((address_space(3))) char*)dst, 16, 0, 0);
}
#define VMCNT0 asm volatile("s_waitcnt vmcnt(0)" ::: "memory")
#define VMW(n) asm volatile("s_waitcnt vmcnt(" #n ")" ::: "memory")
#define FENCE asm volatile("" ::: "memory")
#define RAWBAR do { FENCE; __builtin_amdgcn_s_barrier(); FENCE; } while (0)

DEVI void ln_row(const float* __restrict__ xr, const float* __restrict__ g,
                 const float* __restrict__ be, unsigned short* __restrict__ outr,
                 int tid) {
  float v[3];
  float s = 0.f, s2 = 0.f;
#pragma unroll
  for (int j = 0; j < 3; j++) {
    int i = tid + j * 256;
    v[j] = xr[i];
    s += v[j];
    s2 += v[j] * v[j];
  }
#pragma unroll
  for (int o = 32; o > 0; o >>= 1) {
    s += __shfl_down(s, o);
    s2 += __shfl_down(s2, o);
  }
  __shared__ float sh[8];
  int w = tid >> 6;
  if ((tid & 63) == 0) { sh[w] = s; sh[4 + w] = s2; }
  __syncthreads();
  s = sh[0] + sh[1] + sh[2] + sh[3];
  s2 = sh[4] + sh[5] + sh[6] + sh[7];
  float mu = s * (1.f / C_);
  float var = s2 * (1.f / C_) - mu * mu;
  float rs = rsqrtf(var + 1e-5f);
#pragma unroll
  for (int j = 0; j < 3; j++) {
    int i = tid + j * 256;
    outr[i] = f2bf((v[j] - mu) * rs * g[i] + be[i]);
  }
}

// ---------------- prep: weight transpose+cvt (blocks 0..1727) + LN1 (rest) ----
__global__ __launch_bounds__(256) void prep_kernel(
    const float* __restrict__ a0, unsigned short* __restrict__ o0,
    const float* __restrict__ a1, unsigned short* __restrict__ o1,
    const float* __restrict__ a2, unsigned short* __restrict__ o2,
    const float* __restrict__ a3, unsigned short* __restrict__ o3,
    const float* __restrict__ x, const float* __restrict__ g1,
    const float* __restrict__ be1, unsigned short* __restrict__ xn) {
  int bid = blockIdx.x;
  if (bid >= 1728) {  // LN1 path
    int row = bid - 1728;
    ln_row(x + (long)row * C_, g1, be1, xn + (long)row * C_, threadIdx.x);
    return;
  }
  __shared__ float t[64][65];
  const float* in; unsigned short* out; int K, N, nx;
  if (bid < 432) { in = a0; out = o0; K = 768; N = 2304; nx = 36; }
  else if (bid < 576) { bid -= 432; in = a1; out = o1; K = 768; N = 768; nx = 12; }
  else if (bid < 1152) { bid -= 576; in = a2; out = o2; K = 768; N = 3072; nx = 48; }
  else { bid -= 1152; in = a3; out = o3; K = 3072; N = 768; nx = 12; }
  int n0 = (bid % nx) * 64, k0 = (bid / nx) * 64;
  int tx = threadIdx.x & 63, ty = threadIdx.x >> 6;
#pragma unroll
  for (int r = 0; r < 16; r++) {
    int kr = ty * 16 + r;
    t[kr][tx] = in[(long)(k0 + kr) * N + n0 + tx];
  }
  __syncthreads();
#pragma unroll
  for (int r = 0; r < 16; r++) {
    int nr = ty * 16 + r;
    out[(long)(n0 + nr) * K + k0 + tx] = f2bf(t[tx][nr]);
  }
}

// ---------------- layernorm (768 = 3*256) ----------------
__global__ __launch_bounds__(256) void ln_kernel(const float* __restrict__ x,
                                                 const float* __restrict__ g,
                                                 const float* __restrict__ be,
                                                 unsigned short* __restrict__ out) {
  int row = blockIdx.x;
  ln_row(x + (long)row * C_, g, be, out + (long)row * C_, threadIdx.x);
}

// ---------------- fused attention: swapped QK^T, 3-buffer counted pipeline ----
// (R11 structure — best measured; dump sliced per-bh)
__global__ __launch_bounds__(256) void attn_kernel(
    const unsigned short* __restrict__ qg,
    const unsigned short* __restrict__ kg,
    const unsigned short* __restrict__ vt,
    float* __restrict__ attn,
    unsigned short* __restrict__ ctx,
    float* __restrict__ dump) {
  __shared__ unsigned short Ks[3][64][64];   // 24 KiB
  __shared__ unsigned short Vs[3][64][64];   // 24 KiB
  __shared__ unsigned short Ps[4][16][40];   // 5 KiB
  const int wgid = (blockIdx.x & 7) * (BH_ * QBLK_ / 8) + (blockIdx.x >> 3);
  const int bh = wgid / QBLK_, qb = wgid % QBLK_;
  const int b = bh / H_, h = bh % H_;
  const int tid = threadIdx.x, wave = tid >> 6, lane = tid & 63;
  const int l15 = lane & 15, l4 = lane >> 4;
  const int q0w = qb * 64 + wave * 16;

  const unsigned short* Qh = qg + (long)bh * N_ * D_;
  const char* Kb = (const char*)(kg + (long)bh * N_ * D_);
  const char* Vb = (const char*)(vt + (long)bh * D_ * N_);
  float* dmp = dump + (long)bh * 2048;

  int qrc = q0w + l15; if (qrc >= N_) qrc = N_ - 1;
  bf16x8 qa0 = *(const bf16x8*)(Qh + (long)qrc * D_ + l4 * 8);
  bf16x8 qa1 = *(const bf16x8*)(Qh + (long)qrc * D_ + 32 + l4 * 8);

  auto srcAddr = [&](const char* g0, long rstride, int i) -> const char* {
    int off = i * 4096 + tid * 16;
    int row = off >> 7, colD = off & 127;
    return g0 + (long)row * rstride + (colD ^ ((row & 7) << 4));
  };
  auto stageK = [&](int bu, int kt) {
    const char* g0 = Kb + (long)kt * 8192;
#pragma unroll
    for (int i = 0; i < 2; i++)
      gload16(srcAddr(g0, 128, i), ((char*)Ks) + bu * 8192 + i * 4096 + wave * 1024);
  };
  auto stageV = [&](int bu, int kt) {
    const char* g0 = Vb + (long)kt * 128;
#pragma unroll
    for (int i = 0; i < 2; i++)
      gload16(srcAddr(g0, (long)N_ * 2, i), ((char*)Vs) + bu * 8192 + i * 4096 + wave * 1024);
  };
  auto rdK = [&](int bu, int row, int colb) -> bf16x8 {
    return *(const bf16x8*)(((const char*)Ks) + bu * 8192 + row * 128 +
                            (colb ^ ((row & 7) << 4)));
  };
  auto rdV = [&](int bu, int row, int colb) -> bf16x8 {
    return *(const bf16x8*)(((const char*)Vs) + bu * 8192 + row * 128 +
                            (colb ^ ((row & 7) << 4)));
  };
  auto computeS = [&](int bu, f32x4 (&s)[4]) {
#pragma unroll
    for (int nf = 0; nf < 4; nf++) {
      int row = nf * 16 + l15;
      bf16x8 k0v = rdK(bu, row, l4 * 16);
      bf16x8 k1v = rdK(bu, row, 64 + l4 * 16);
      f32x4 z = {0.f, 0.f, 0.f, 0.f};
      z = __builtin_amdgcn_mfma_f32_16x16x32_bf16(k0v, qa0, z, 0, 0, 0);
      z = __builtin_amdgcn_mfma_f32_16x16x32_bf16(k1v, qa1, z, 0, 0, 0);
      s[nf] = z;
    }
  };
  auto maskLast = [&](f32x4 (&s)[4]) {  // kv tile 9: only kv=576 valid
#pragma unroll
    for (int nf = 0; nf < 4; nf++)
#pragma unroll
      for (int r = 0; r < 4; r++) {
        if (nf == 0 && r == 0)
          s[nf][r] = (l4 == 0) ? s[nf][r] : -1e30f;
        else
          s[nf][r] = -1e30f;
      }
  };

  // ---------- pass 1: K only, lane-local stats, 3-buffer depth-2 pipeline ----
  float m_ln = -1e30f, l_ln = 0.f;
  stageK(0, 0); stageK(1, 1);
#pragma unroll
  for (int kt = 0; kt < KVT_; kt++) {
    if (kt < KVT_ - 1) { VMW(2); } else { VMW(0); }
    RAWBAR;
    if (kt + 2 < KVT_) stageK((kt + 2) % 3, kt + 2);
    f32x4 s[4];
    computeS(kt % 3, s);
    if (kt == KVT_ - 1) maskLast(s);
    float mt = s[0][0];
#pragma unroll
    for (int nf = 0; nf < 4; nf++)
#pragma unroll
      for (int r = 0; r < 4; r++) mt = fmaxf(mt, s[nf][r]);
    float mn = fmaxf(m_ln, mt);
    float acc = 0.f;
#pragma unroll
    for (int nf = 0; nf < 4; nf++)
#pragma unroll
      for (int r = 0; r < 4; r++) acc += __expf(s[nf][r] - mn);
    l_ln = l_ln * __expf(m_ln - mn) + acc;
    m_ln = mn;
  }

  RAWBAR;  // all pass-1 LDS reads retired before restaging
  stageK(0, 0); stageV(0, 0); stageK(1, 1); stageV(1, 1);

  // cross-lane reduce over l4 group (overlaps prologue load latency)
  float m = fmaxf(m_ln, __shfl_xor(m_ln, 16));
  m = fmaxf(m, __shfl_xor(m, 32));
  float lr = l_ln * __expf(m_ln - m);
  lr += __shfl_xor(lr, 16);
  lr += __shfl_xor(lr, 32);
  float inv_l = 1.f / lr;

  // ---------- pass 2: P emit (from regs) + PV, 3-buffer depth-2 pipeline ----
  f32x4 cacc[4];
#pragma unroll
  for (int nf = 0; nf < 4; nf++) cacc[nf] = f32x4{0.f, 0.f, 0.f, 0.f};

  const int qv = q0w + l15;
  const bool qok = qv < N_;
  float* prow = attn + ((long)bh * N_ + (qok ? qv : 0)) * N_;

#pragma unroll
  for (int kt = 0; kt < KVT_; kt++) {
    const int bu = kt % 3;
    // gate: KV(kt) done. In-order pending after it: st(kt-2), KV(kt+1), st(kt-1)
    if (kt == 0) { VMW(4); }
    else if (kt == 1) { VMW(8); }
    else if (kt < KVT_ - 1) { VMW(12); }
    else { VMW(8); }
    RAWBAR;
    if (kt + 2 < KVT_) { stageK((kt + 2) % 3, kt + 2); stageV((kt + 2) % 3, kt + 2); }
    f32x4 s[4];
    computeS(bu, s);
    if (kt == KVT_ - 1) maskLast(s);
    float p[4][4];
#pragma unroll
    for (int nf = 0; nf < 4; nf++)
#pragma unroll
      for (int r = 0; r < 4; r++) p[nf][r] = __expf(s[nf][r] - m) * inv_l;

    // P store directly from registers; wave-uniform op count (per-bh dump clamp)
    if (kt < KVT_ - 1) {
#pragma unroll
      for (int nf = 0; nf < 4; nf++) {
        f32x4u val;
        val[0] = p[nf][0]; val[1] = p[nf][1]; val[2] = p[nf][2]; val[3] = p[nf][3];
        float* a = qok ? (prow + kt * 64 + nf * 16 + l4 * 4) : (dmp + tid * 4);
        *(f32x4u*)a = val;
      }
    } else {
      float* a = (qok && l4 == 0) ? (prow + 576) : (dmp + tid);
      *a = p[0][0];
    }

    // PV A-frag: P row (q=l15) packed bf16 (truncation) -> Ps, then b128 reads
#pragma unroll
    for (int nf = 0; nf < 4; nf++) {
      unsigned lo = (__float_as_uint(p[nf][1]) & 0xffff0000u) |
                    (__float_as_uint(p[nf][0]) >> 16);
      unsigned hi = (__float_as_uint(p[nf][3]) & 0xffff0000u) |
                    (__float_as_uint(p[nf][2]) >> 16);
      *(uint2*)&Ps[wave][l15][nf * 16 + l4 * 4] = uint2{lo, hi};
    }
#pragma unroll
    for (int ks = 0; ks < 2; ks++) {
      bf16x8 pa = *(const bf16x8*)&Ps[wave][l15][ks * 32 + l4 * 8];
#pragma unroll
      for (int nf = 0; nf < 4; nf++) {
        bf16x8 vb = rdV(bu, nf * 16 + l15, ks * 64 + l4 * 16);
        cacc[nf] = __builtin_amdgcn_mfma_f32_16x16x32_bf16(pa, vb, cacc[nf], 0, 0, 0);
      }
    }
  }

  // ---------- ctx write (row = q = l4*4+r, col = d = nf*16+l15) ----------
#pragma unroll
  for (int nf = 0; nf < 4; nf++)
#pragma unroll
    for (int r = 0; r < 4; r++) {
      int qw = q0w + l4 * 4 + r;
      if (qw >= N_) continue;
      int d = nf * 16 + l15;
      ctx[((long)b * N_ + qw) * C_ + h * D_ + d] = f2bf(cacc[nf][r]);
    }
}

// ---------------- 128x128 MFMA GEMM, counted-vmcnt 2-phase ----------------
template <int EPI>
__global__ __launch_bounds__(256) void gemm128(
    const unsigned short* __restrict__ A,
    const unsigned short* __restrict__ BT,
    int M, int K, int Nc,
    void* __restrict__ outp, const float* __restrict__ bias,
    const float* __restrict__ resid) {
  __shared__ unsigned short As[2][128][64];
  __shared__ unsigned short Bs[2][128][64];
  const int tid = threadIdx.x, wave = tid >> 6, lane = tid & 63;
  const int l15 = lane & 15, l4 = lane >> 4;
  const long m0 = (long)blockIdx.y * 128, n0 = (long)blockIdx.x * 128;
  const int wr = (wave >> 1) * 64, wc = (wave & 1) * 64;

  f32x4 acc[4][4];
#pragma unroll
  for (int i = 0; i < 4; i++)
#pragma unroll
    for (int j = 0; j < 4; j++) acc[i][j] = f32x4{0.f, 0.f, 0.f, 0.f};

  auto stageA = [&](int buf, int t) {
#pragma unroll
    for (int i = 0; i < 4; i++) {
      int off = i * 4096 + tid * 16;
      int row = off >> 7, colD = off & 127;
      long gr = m0 + row; if (gr >= M) gr = M - 1;
      const char* src = (const char*)A + (gr * (long)K + (long)t * 64) * 2 +
                        (colD ^ ((row & 7) << 4));
      char* dst = ((char*)As) + buf * 16384 + i * 4096 + wave * 1024;
      gload16(src, dst);
    }
  };
  auto stageB = [&](int buf, int t) {
#pragma unroll
    for (int i = 0; i < 4; i++) {
      int off = i * 4096 + tid * 16;
      int row = off >> 7, colD = off & 127;
      const char* src = (const char*)BT + ((n0 + row) * (long)K + (long)t * 64) * 2 +
                        (colD ^ ((row & 7) << 4));
      char* dst = ((char*)Bs) + buf * 16384 + i * 4096 + wave * 1024;
      gload16(src, dst);
    }
  };

  const int nt = K / 64;
  stageA(0, 0); stageB(0, 0);
  int buf = 0;
  for (int t = 0; t < nt; t++) {
    if (t + 1 < nt) {
      stageA(buf ^ 1, t + 1); stageB(buf ^ 1, t + 1);
      VMW(8);
    } else {
      VMCNT0;
    }
    RAWBAR;
    bf16x8 af[4][2], bfr[4][2];
#pragma unroll
    for (int mf = 0; mf < 4; mf++)
#pragma unroll
      for (int kk = 0; kk < 2; kk++) {
        int row = wr + mf * 16 + l15, colb = kk * 64 + l4 * 16;
        af[mf][kk] = *(const bf16x8*)(((const char*)As) + buf * 16384 + row * 128 +
                                      (colb ^ ((row & 7) << 4)));
      }
#pragma unroll
    for (int nf = 0; nf < 4; nf++)
#pragma unroll
      for (int kk = 0; kk < 2; kk++) {
        int row = wc + nf * 16 + l15, colb = kk * 64 + l4 * 16;
        bfr[nf][kk] = *(const bf16x8*)(((const char*)Bs) + buf * 16384 + row * 128 +
                                       (colb ^ ((row & 7) << 4)));
      }
#pragma unroll
    for (int kk = 0; kk < 2; kk++)
#pragma unroll
      for (int mf = 0; mf < 4; mf++)
#pragma unroll
        for (int nf = 0; nf < 4; nf++)
          acc[mf][nf] =
              __builtin_amdgcn_mfma_f32_16x16x32_bf16(af[mf][kk], bfr[nf][kk], acc[mf][nf], 0, 0, 0);
    RAWBAR;
    buf ^= 1;
  }

#pragma unroll
  for (int mf = 0; mf < 4; mf++)
#pragma unroll
    for (int nf = 0; nf < 4; nf++)
#pragma unroll
      for (int r = 0; r < 4; r++) {
        long row = m0 + wr + mf * 16 + l4 * 4 + r;
        long col = n0 + wc + nf * 16 + l15;
        if (row >= M) continue;
        float v = acc[mf][nf][r];
        if constexpr (EPI == 3 || EPI == 5) {
          float* o = (float*)outp;
          long idx = row * (long)Nc + col;
          o[idx] = v + bias[col] + resid[idx];
        } else if constexpr (EPI == 4) {
          v += bias[col];
          float ge = 0.5f * v * (1.f + erff(v * 0.70710678118654752f));
          ((unsigned short*)outp)[row * (long)Nc + col] = f2bf(ge);
        }
      }
}

// ---------------- 256x256 8-phase MFMA GEMM ----------------
template <int EPI>
__global__ __launch_bounds__(512, 2) void gemm256(
    const unsigned short* __restrict__ A,
    const unsigned short* __restrict__ BT,
    int M, int K, int Nc,
    void* __restrict__ outp, const float* __restrict__ bias,
    const float* __restrict__ resid) {
  __shared__ unsigned short smem[2][2][2][128][64];
  const int tid = threadIdx.x, wave = tid >> 6, lane = tid & 63;
  const int l15 = lane & 15, l4 = lane >> 4;
  const int wm = wave >> 2, wn = wave & 3;

  const int nbx = gridDim.x;
  const int nwg = nbx * gridDim.y;
  int orig = blockIdx.y * nbx + blockIdx.x;
  int qq = nwg >> 3, r8 = nwg & 7;
  int xcd = orig & 7, idx = orig >> 3;
  int wg = (xcd < r8 ? xcd * (qq + 1) : r8 * (qq + 1) + (xcd - r8) * qq) + idx;
  const long m0 = (long)(wg / nbx) * 256;
  const long n0 = (long)(wg % nbx) * 256;

  f32x4 acc[2][2][4][2];
#pragma unroll
  for (int a = 0; a < 2; a++)
#pragma unroll
    for (int b = 0; b < 2; b++)
#pragma unroll
      for (int m = 0; m < 4; m++)
#pragma unroll
        for (int n = 0; n < 2; n++) acc[a][b][m][n] = f32x4{0.f, 0.f, 0.f, 0.f};

  auto stage = [&](int d, int op, int half, int t) {
#pragma unroll
    for (int it = 0; it < 2; it++) {
      int off = it * 8192 + tid * 16;
      int lrow = off >> 7, colb = off & 127;
      long grow;
      if (op == 0) {
        grow = m0 + half * 128 + lrow;
        if (grow >= M) grow = M - 1;
      } else {
        grow = n0 + half * 128 + lrow;
      }
      const unsigned short* gp = (op == 0) ? A : BT;
      const char* src = (const char*)(gp + grow * (long)K + (long)t * 64) +
                        (colb ^ ((lrow & 7) << 4));
      char* dst = ((char*)smem) + (((d * 2 + op) * 2 + half) * 16384) + off;
      gload16(src, dst);
    }
  };
  auto rdfrag = [&](int d, int op, int half, int lr, int kk) -> bf16x8 {
    const char* p = ((const char*)smem) + (((d * 2 + op) * 2 + half) * 16384) + lr * 128 +
                    ((kk * 64 + l4 * 16) ^ ((lr & 7) << 4));
    return *(const bf16x8*)p;
  };

  bf16x8 av[4][2];

#define PHASE(d, qm, qn, STAGECODE, VMCODE)                                              \
  {                                                                                      \
    if constexpr (qn == 0) {                                                             \
      _Pragma("unroll") for (int m = 0; m < 4; m++)                                      \
          _Pragma("unroll") for (int kk = 0; kk < 2; kk++)                               \
              av[m][kk] = rdfrag(d, 0, qm, wm * 64 + m * 16 + l15, kk);                  \
    }                                                                                    \
    bf16x8 bv[2][2];                                                                     \
    _Pragma("unroll") for (int n = 0; n < 2; n++)                                        \
        _Pragma("unroll") for (int kk = 0; kk < 2; kk++)                                 \
            bv[n][kk] = rdfrag(d, 1, qn, wn * 32 + n * 16 + l15, kk);                    \
    STAGECODE;                                                                           \
    VMCODE;                                                                              \
    RAWBAR;                                                                              \
    __builtin_amdgcn_s_setprio(1);                                                       \
    _Pragma("unroll") for (int kk = 0; kk < 2; kk++)                                     \
        _Pragma("unroll") for (int m = 0; m < 4; m++)                                    \
            _Pragma("unroll") for (int n = 0; n < 2; n++)                                \
                acc[qm][qn][m][n] = __builtin_amdgcn_mfma_f32_16x16x32_bf16(             \
                    av[m][kk], bv[n][kk], acc[qm][qn][m][n], 0, 0, 0);                   \
    __builtin_amdgcn_s_setprio(0);                                                       \
    RAWBAR;                                                                              \
  }

  const int nt = K / 64, ni = nt / 2;
  stage(0, 0, 0, 0); stage(0, 0, 1, 0); stage(0, 1, 0, 0); stage(0, 1, 1, 0);
  stage(1, 0, 0, 1); stage(1, 0, 1, 1); stage(1, 1, 0, 1); stage(1, 1, 1, 1);
  asm volatile("s_waitcnt vmcnt(8)" ::: "memory");
  RAWBAR;

  for (int i = 0; i < ni; i++) {
    const int t1 = 2 * i + 1, t2 = 2 * i + 2, t3 = 2 * i + 3;
    PHASE(0, 0, 0, { if (i > 0) stage(1, 0, 1, t1); }, {});
    PHASE(0, 0, 1, { if (i > 0) stage(1, 1, 1, t1); }, {});
    PHASE(0, 1, 0, { if (t2 < nt) stage(0, 0, 0, t2); }, {});
    PHASE(0, 1, 1, { if (t2 < nt) stage(0, 1, 0, t2); },
          { if (t2 < nt) { asm volatile("s_waitcnt vmcnt(4)" ::: "memory"); }
            else { asm volatile("s_waitcnt vmcnt(0)" ::: "memory"); } });
    PHASE(1, 0, 0, { if (t2 < nt) stage(0, 0, 1, t2); }, {});
    PHASE(1, 0, 1, { if (t2 < nt) stage(0, 1, 1, t2); }, {});
    PHASE(1, 1, 0, { if (t3 < nt) stage(1, 0, 0, t3); }, {});
    PHASE(1, 1, 1, { if (t3 < nt) stage(1, 1, 0, t3); },
          { if (t3 < nt) { asm volatile("s_waitcnt vmcnt(4)" ::: "memory"); }
            else { asm volatile("s_waitcnt vmcnt(0)" ::: "memory"); } });
  }
#undef PHASE

#pragma unroll
  for (int qm = 0; qm < 2; qm++)
#pragma unroll
    for (int qn = 0; qn < 2; qn++)
#pragma unroll
      for (int m = 0; m < 4; m++)
#pragma unroll
        for (int n = 0; n < 2; n++)
#pragma unroll
          for (int r = 0; r < 4; r++) {
            long row = m0 + qm * 128 + wm * 64 + m * 16 + l4 * 4 + r;
            long col = n0 + qn * 128 + wn * 32 + n * 16 + l15;
            if (row >= M) continue;
            float v = acc[qm][qn][m][n][r];
            if constexpr (EPI == 0) {
              v += bias[col];
              int which = (int)col / C_;
              int rem = (int)col % C_;
              int hh = rem >> 6, d = rem & 63;
              int bb = (int)row / N_, nn = (int)row % N_;
              if (which == 0) v *= 0.125f;
              unsigned short* o = (unsigned short*)outp;
              long base = (long)which * ((long)BH_ * N_ * D_);
              long oidx;
              if (which < 2)
                oidx = base + (((long)(bb * H_ + hh)) * N_ + nn) * D_ + d;
              else
                oidx = base + (((long)(bb * H_ + hh)) * D_ + d) * N_ + nn;
              o[oidx] = f2bf(v);
            } else if constexpr (EPI == 4) {
              v += bias[col];
              float ge = 0.5f * v * (1.f + erff(v * 0.70710678118654752f));
              ((unsigned short*)outp)[row * (long)Nc + col] = f2bf(ge);
            } else {
              float* o = (float*)outp;
              long oidx = row * (long)Nc + col;
              o[oidx] = v + bias[col] + resid[oidx];
            }
          }
}

// ---------------- launch ----------------
extern "C" void kernel_launch(void* const* d_in, const int* in_sizes, int n_in,
                              void* d_out, int out_size, void* d_ws, size_t ws_size,
                              hipStream_t stream) {
  const float* x = (const float*)d_in[0];
  const float* w_qkv = (const float*)d_in[1];
  const float* b_qkv = (const float*)d_in[2];
  const float* w_proj = (const float*)d_in[3];
  const float* b_proj = (const float*)d_in[4];
  const float* g1 = (const float*)d_in[5];
  const float* be1 = (const float*)d_in[6];
  const float* g2 = (const float*)d_in[7];
  const float* be2 = (const float*)d_in[8];
  const float* w1 = (const float*)d_in[9];
  const float* b1 = (const float*)d_in[10];
  const float* w2 = (const float*)d_in[11];
  const float* b2 = (const float*)d_in[12];

  char* ws = (char*)d_ws;
  const size_t SZ_TOK_BF = (size_t)ROWS_ * C_ * 2;
  unsigned short* xn = (unsigned short*)(ws);
  unsigned short* q = (unsigned short*)(ws + SZ_TOK_BF);      // [BH][N][D]
  unsigned short* v = (unsigned short*)(ws + 3 * SZ_TOK_BF);  // [BH][D][N]
  unsigned short* ctx = (unsigned short*)(ws + 4 * SZ_TOK_BF);
  unsigned short* hbuf = q;  // reuse q/k/v/ctx area for MLP hidden
  float* x1 = (float*)(ws + 5 * SZ_TOK_BF);
  unsigned short* wqkvT = (unsigned short*)(ws + 5 * SZ_TOK_BF + (size_t)ROWS_ * C_ * 4);
  unsigned short* wprojT = wqkvT + (size_t)C_ * 3 * C_;
  unsigned short* w1T = wprojT + (size_t)C_ * C_;
  unsigned short* w2T = w1T + (size_t)C_ * HID_;
  float* dump = (float*)(w2T + (size_t)HID_ * C_);  // 192 x 8 KiB per-bh dump

  float* out_x = (float*)d_out;
  float* attn = out_x + (size_t)ROWS_ * C_;

  // fused: weight cvt/transpose + LN1
  prep_kernel<<<1728 + ROWS_, 256, 0, stream>>>(w_qkv, wqkvT, w_proj, wprojT, w1, w1T,
                                                w2, w2T, x, g1, be1, xn);

  {  // QKV: 8-phase 256^2
    dim3 g(3 * C_ / 256, (ROWS_ + 255) / 256);
    gemm256<0><<<g, 512, 0, stream>>>(xn, wqkvT, ROWS_, C_, 3 * C_, q, b_qkv, nullptr);
  }
  attn_kernel<<<BH_ * QBLK_, 256, 0, stream>>>(q, q + (size_t)BH_ * N_ * D_, v, attn, ctx,
                                               dump);
  {  // proj + residual
    dim3 g(C_ / 128, (ROWS_ + 127) / 128);
    gemm128<3><<<g, 256, 0, stream>>>(ctx, wprojT, ROWS_, C_, C_, x1, b_proj, x);
  }
  ln_kernel<<<ROWS_, 256, 0, stream>>>(x1, g2, be2, xn);
  {  // mlp1 + gelu: 8-phase 256^2
    dim3 g(HID_ / 256, (ROWS_ + 255) / 256);
    gemm256<4><<<g, 512, 0, stream>>>(xn, w1T, ROWS_, C_, HID_, hbuf, b1, nullptr);
  }
  {  // mlp2 + residual -> out_x
    dim3 g(C_ / 128, (ROWS_ + 127) / 128);
    gemm128<5><<<g, 256, 0, stream>>>(hbuf, w2T, ROWS_, HID_, C_, out_x, b2, x1);
  }
}